// Round 4
// baseline (141.913 us; speedup 1.0000x reference)
//
#include <hip/hip_runtime.h>
#include <hip/hip_bf16.h>

// MMD loss via bf16 MFMA Gram matrix, exp-underflow-skipped epilogue, 2 launches.
// z = [xf; yf] (8192 x 256). result = (1/4096^2) * (8192*NSIG + sum_{i<j} 2 s_i s_j K_ij)
// ws: [0,4MiB) bf16 Z[8192][256]; float norms[8192]; double acc; uint counter.

#define NSIG 5
#define NT   64
#define NBLK ((NT * (NT + 1)) / 2)   // 2080

typedef __attribute__((ext_vector_type(8))) short short8;
typedef __attribute__((ext_vector_type(4))) float floatx4;

__device__ __forceinline__ void glds16(const ushort* g, ushort* l) {
    __builtin_amdgcn_global_load_lds((const __attribute__((address_space(1))) void*)g,
                                     (__attribute__((address_space(3))) void*)l,
                                     16, 0, 0);
}

// ---- prep: (B,C,H,W) fp32 -> Z[n][c] bf16 row-major + norms, via LDS transpose ----
// 512 blocks, each handles one (s, b, 16-row p-strip): [256 c][16 p] fp32 tile.
__global__ __launch_bounds__(256) void prep_kernel(const float* __restrict__ x,
                                                   const float* __restrict__ y,
                                                   ushort* __restrict__ Z,
                                                   float* __restrict__ norms,
                                                   double* __restrict__ acc,
                                                   uint* __restrict__ counter) {
    const int bid = blockIdx.x;           // s(1) | b(2) | strip(6)
    const int t = threadIdx.x;
    if (bid == 0 && t == 0) { *acc = 0.0; *counter = 0u; }
    const int s = bid >> 8;
    const int b = (bid >> 6) & 3;
    const int p0 = (bid & 63) << 4;
    const float* src = s ? y : x;
    const int n0 = (s << 12) + (b << 10) + p0;

    __shared__ float tile[256][17];

    // load: thread (cg = t>>2, p4 = (t&3)*4) reads float4; 4 c-passes
    const int cg = t >> 2;
    const int p4 = (t & 3) << 2;
#pragma unroll
    for (int pass = 0; pass < 4; ++pass) {
        const int c = cg + (pass << 6);
        const float4 v = *(const float4*)(src + (((size_t)((b << 8) + c)) << 10) + p0 + p4);
        tile[c][p4] = v.x; tile[c][p4 + 1] = v.y; tile[c][p4 + 2] = v.z; tile[c][p4 + 3] = v.w;
    }
    __syncthreads();

    // store: thread (r = t>>4, q = t&15) packs 2 chunks of 8 c's for row n0+r
    const int r = t >> 4;
    const int q = t & 15;
    float nsum = 0.f;
#pragma unroll
    for (int h = 0; h < 2; ++h) {
        const int c0 = (q + (h << 4)) << 3;       // 8q or 128+8q
        uint pk[4];
#pragma unroll
        for (int j = 0; j < 4; ++j) {
            const float f0 = tile[c0 + 2 * j][r];
            const float f1 = tile[c0 + 2 * j + 1][r];
            const __hip_bfloat16 h0 = __float2bfloat16(f0);
            const __hip_bfloat16 h1 = __float2bfloat16(f1);
            const float q0 = __bfloat162float(h0), q1 = __bfloat162float(h1);
            nsum = fmaf(q0, q0, nsum);
            nsum = fmaf(q1, q1, nsum);
            pk[j] = (uint)(*(const ushort*)&h0) | ((uint)(*(const ushort*)&h1) << 16);
        }
        *(uint4*)(Z + (size_t)(n0 + r) * 256 + c0) = make_uint4(pk[0], pk[1], pk[2], pk[3]);
    }
    // norm: reduce across the 16 lanes sharing row r (lanes are consecutive)
#pragma unroll
    for (int off = 1; off < 16; off <<= 1) nsum += __shfl_xor(nsum, off, 64);
    if (q == 0) norms[n0 + r] = nsum;
}

// ---- GEMM (bf16 MFMA, double-buffered glds) + skip-list epilogue + last-block finalize ----
__global__ __launch_bounds__(256) void gemm_epi(const ushort* __restrict__ Z,
                                                const float* __restrict__ norms,
                                                const float* __restrict__ sigmas,
                                                double* __restrict__ acc,
                                                uint* __restrict__ counter,
                                                float* __restrict__ out) {
    __shared__ ushort lA[2][4096];
    __shared__ ushort lB[2][4096];
    __shared__ float wsum[4];

    const int L = blockIdx.x;
#define TRI(b) ((b) * NT - ((b) * ((b) - 1)) / 2)
    int bi = (int)((129.0f - sqrtf((float)(129 * 129 - 8 * L))) * 0.5f);
    if (bi < 0) bi = 0;
    if (bi > NT - 1) bi = NT - 1;
    while (TRI(bi + 1) <= L) ++bi;
    while (TRI(bi) > L) --bi;
    const int bj = bi + (L - TRI(bi));

    const int i0 = bi << 7, j0 = bj << 7;
    const int t = threadIdx.x;
    const int w = t >> 6, l = t & 63;
    const int wi = w >> 1, wj = w & 1;

    // staging: wave w owns rows [w*32, w*32+32); swizzle chunk c ^= (row>>1)&3 (2-way = free)
    const int rs0 = (w << 5) + (l >> 2);
    const int kq = ((l & 3) ^ ((l >> 3) & 3)) << 3;
    const ushort* gA0 = Z + (size_t)(i0 + rs0) * 256 + kq;
    const ushort* gA1 = gA0 + 16 * 256;
    const ushort* gB0 = Z + (size_t)(j0 + rs0) * 256 + kq;
    const ushort* gB1 = gB0 + 16 * 256;
    const int ldo0 = (w << 5) << 5;
    const int ldo1 = ldo0 + (16 << 5);

    const int lane_m = l & 15, lane_q = l >> 4;
    int aoff[4], boff[4];
#pragma unroll
    for (int f = 0; f < 4; ++f) {
        const int ra = (wi << 6) + (f << 4) + lane_m;
        aoff[f] = (ra << 5) + ((lane_q ^ ((ra >> 1) & 3)) << 3);
        const int rb = (wj << 6) + (f << 4) + lane_m;
        boff[f] = (rb << 5) + ((lane_q ^ ((rb >> 1) & 3)) << 3);
    }

    floatx4 accf[4][4];
#pragma unroll
    for (int fi = 0; fi < 4; ++fi)
#pragma unroll
        for (int fj = 0; fj < 4; ++fj) accf[fi][fj] = (floatx4){0.f, 0.f, 0.f, 0.f};

    glds16(gA0, &lA[0][ldo0]); glds16(gA1, &lA[0][ldo1]);
    glds16(gB0, &lB[0][ldo0]); glds16(gB1, &lB[0][ldo1]);

    for (int ck = 0; ck < 8; ++ck) {
        const int cur = ck & 1;
        __syncthreads();
        if (ck < 7) {
            const int nxt = cur ^ 1;
            const int ko = (ck + 1) << 5;
            glds16(gA0 + ko, &lA[nxt][ldo0]); glds16(gA1 + ko, &lA[nxt][ldo1]);
            glds16(gB0 + ko, &lB[nxt][ldo0]); glds16(gB1 + ko, &lB[nxt][ldo1]);
        }
        short8 af[4], bfr[4];
#pragma unroll
        for (int f = 0; f < 4; ++f) {
            af[f]  = *(const short8*)(&lA[cur][aoff[f]]);
            bfr[f] = *(const short8*)(&lB[cur][boff[f]]);
        }
#pragma unroll
        for (int fi = 0; fi < 4; ++fi)
#pragma unroll
            for (int fj = 0; fj < 4; ++fj)
                accf[fi][fj] = __builtin_amdgcn_mfma_f32_16x16x32_bf16(af[fi], bfr[fj], accf[fi][fj], 0, 0, 0);
    }

    // ---- epilogue ----
    float c2[NSIG];
#pragma unroll
    for (int k = 0; k < NSIG; ++k) c2[k] = (-0.5f / sigmas[k]) * 1.44269504f;

    const float* nA = norms + i0 + (wi << 6);
    const float* nB = norms + j0 + (wj << 6);
    const bool diag = (bi == bj);
    const float sgn2 = ((bi < 32) == (bj < 32)) ? 2.f : -2.f;

#pragma unroll
    for (int fi = 0; fi < 4; ++fi) {
        const floatx4 ni4 = *(const floatx4*)(nA + (fi << 4) + (lane_q << 2));
#pragma unroll
        for (int fj = 0; fj < 4; ++fj) {
            const float njs = nB[(fj << 4) + lane_m];
#pragma unroll
            for (int v = 0; v < 4; ++v) {
                float d = fmaf(-2.f, accf[fi][fj][v], ni4[v] + njs);
                d = fmaxf(d, 0.f);
                if (diag) {
                    const int dif = ((wi - wj) << 6) + ((fi - fj) << 4) + ((lane_q << 2) + v) - lane_m;
                    d = (dif < 0) ? d : 3.0e9f;   // keep strictly-upper pairs only
                }
                accf[fi][fj][v] = d;
            }
        }
    }

    float dmin = accf[0][0][0];
#pragma unroll
    for (int fi = 0; fi < 4; ++fi)
#pragma unroll
        for (int fj = 0; fj < 4; ++fj)
#pragma unroll
            for (int v = 0; v < 4; ++v) dmin = fminf(dmin, accf[fi][fj][v]);
#pragma unroll
    for (int off = 1; off < 64; off <<= 1) dmin = fminf(dmin, __shfl_xor(dmin, off, 64));

    float lsum = 0.f;
#pragma unroll
    for (int k = 0; k < NSIG; ++k) {
        if (c2[k] * dmin >= -126.f) {      // wave-uniform: skip if every exp underflows (exact in fp32)
#pragma unroll
            for (int fi = 0; fi < 4; ++fi)
#pragma unroll
                for (int fj = 0; fj < 4; ++fj)
#pragma unroll
                    for (int v = 0; v < 4; ++v)
                        lsum += __builtin_amdgcn_exp2f(c2[k] * accf[fi][fj][v]);
        }
    }
    lsum *= sgn2;

#pragma unroll
    for (int off = 32; off > 0; off >>= 1) lsum += __shfl_down(lsum, off, 64);
    if (l == 0) wsum[w] = lsum;
    __syncthreads();
    if (t == 0) {
        atomicAdd(acc, (double)(wsum[0] + wsum[1] + wsum[2] + wsum[3]));
        __threadfence();
        const uint old = atomicAdd(counter, 1u);
        if (old == NBLK - 1) {
            const double tot = atomicAdd(acc, 0.0);   // all adds visible: counter full after fences
            out[0] = (float)((tot + 8192.0 * NSIG) * (1.0 / (4096.0 * 4096.0)));
        }
    }
}

extern "C" void kernel_launch(void* const* d_in, const int* in_sizes, int n_in,
                              void* d_out, int out_size, void* d_ws, size_t ws_size,
                              hipStream_t stream) {
    const float* x   = (const float*)d_in[0];
    const float* y   = (const float*)d_in[1];
    const float* sig = (const float*)d_in[2];

    ushort* Z     = (ushort*)d_ws;                                   // 4 MiB
    float* norms  = (float*)((char*)d_ws + (size_t)8192 * 256 * 2);  // 32 KiB
    double* acc   = (double*)((char*)norms + 8192 * sizeof(float));
    uint* counter = (uint*)((char*)acc + sizeof(double));
    float* out    = (float*)d_out;

    prep_kernel<<<512, 256, 0, stream>>>(x, y, Z, norms, acc, counter);
    gemm_epi<<<NBLK, 256, 0, stream>>>(Z, norms, sig, acc, counter, out);
}

// Round 5
// 123.174 us; speedup vs baseline: 1.1521x; 1.1521x over previous
//
#include <hip/hip_runtime.h>
#include <hip/hip_bf16.h>

// MMD loss via bf16 MFMA Gram matrix, exp-underflow-skipped epilogue, 3 launches.
// z = [xf; yf] (8192 x 256). result = (1/4096^2) * (8192*NSIG + sum_{i<j} 2 s_i s_j K_ij)
// ws: [0,4MiB) bf16 Z[8192][256]; float norms[8192]; double acc.
//
// R4 lesson: NO per-block __threadfence in the hot kernel (L2 writeback poisons
// resident waves: 53->85us). Finalize is its own kernel.
// R5: single-buffered staging (16.9KB LDS) + __launch_bounds__(256,5) -> 5 blocks/CU.

#define NSIG 5
#define NT   64
#define NBLK ((NT * (NT + 1)) / 2)   // 2080

typedef __attribute__((ext_vector_type(8))) short short8;
typedef __attribute__((ext_vector_type(4))) float floatx4;

__device__ __forceinline__ void glds16(const ushort* g, ushort* l) {
    __builtin_amdgcn_global_load_lds((const __attribute__((address_space(1))) void*)g,
                                     (__attribute__((address_space(3))) void*)l,
                                     16, 0, 0);
}

// ---- prep: (B,C,H,W) fp32 -> Z[n][c] bf16 row-major + norms, via LDS transpose ----
// 512 blocks, each one (s, b, 16-row p-strip): [256 c][16 p] fp32 tile.
__global__ __launch_bounds__(256) void prep_kernel(const float* __restrict__ x,
                                                   const float* __restrict__ y,
                                                   ushort* __restrict__ Z,
                                                   float* __restrict__ norms,
                                                   double* __restrict__ acc) {
    const int bid = blockIdx.x;           // s(1) | b(2) | strip(6)
    const int t = threadIdx.x;
    if (bid == 0 && t == 0) *acc = 0.0;
    const int s = bid >> 8;
    const int b = (bid >> 6) & 3;
    const int p0 = (bid & 63) << 4;
    const float* src = s ? y : x;
    const int n0 = (s << 12) + (b << 10) + p0;

    __shared__ float tile[256][17];

    const int cg = t >> 2;
    const int p4 = (t & 3) << 2;
#pragma unroll
    for (int pass = 0; pass < 4; ++pass) {
        const int c = cg + (pass << 6);
        const float4 v = *(const float4*)(src + (((size_t)((b << 8) + c)) << 10) + p0 + p4);
        tile[c][p4] = v.x; tile[c][p4 + 1] = v.y; tile[c][p4 + 2] = v.z; tile[c][p4 + 3] = v.w;
    }
    __syncthreads();

    const int r = t >> 4;
    const int q = t & 15;
    float nsum = 0.f;
#pragma unroll
    for (int h = 0; h < 2; ++h) {
        const int c0 = (q + (h << 4)) << 3;
        uint pk[4];
#pragma unroll
        for (int j = 0; j < 4; ++j) {
            const float f0 = tile[c0 + 2 * j][r];
            const float f1 = tile[c0 + 2 * j + 1][r];
            const __hip_bfloat16 h0 = __float2bfloat16(f0);
            const __hip_bfloat16 h1 = __float2bfloat16(f1);
            const float q0 = __bfloat162float(h0), q1 = __bfloat162float(h1);
            nsum = fmaf(q0, q0, nsum);
            nsum = fmaf(q1, q1, nsum);
            pk[j] = (uint)(*(const ushort*)&h0) | ((uint)(*(const ushort*)&h1) << 16);
        }
        *(uint4*)(Z + (size_t)(n0 + r) * 256 + c0) = make_uint4(pk[0], pk[1], pk[2], pk[3]);
    }
#pragma unroll
    for (int off = 1; off < 16; off <<= 1) nsum += __shfl_xor(nsum, off, 64);
    if (q == 0) norms[n0 + r] = nsum;
}

// ---- GEMM (bf16 MFMA, single-buffered glds, 5 blocks/CU) + skip-list epilogue ----
__global__ __launch_bounds__(256, 5) void gemm_epi(const ushort* __restrict__ Z,
                                                   const float* __restrict__ norms,
                                                   const float* __restrict__ sigmas,
                                                   double* __restrict__ acc) {
    __shared__ ushort lA[4096];   // 128 rows x 32 k, 8KB
    __shared__ ushort lB[4096];
    __shared__ float wsum[4];

    const int L = blockIdx.x;
#define TRI(b) ((b) * NT - ((b) * ((b) - 1)) / 2)
    int bi = (int)((129.0f - sqrtf((float)(129 * 129 - 8 * L))) * 0.5f);
    if (bi < 0) bi = 0;
    if (bi > NT - 1) bi = NT - 1;
    while (TRI(bi + 1) <= L) ++bi;
    while (TRI(bi) > L) --bi;
    const int bj = bi + (L - TRI(bi));

    const int i0 = bi << 7, j0 = bj << 7;
    const int t = threadIdx.x;
    const int w = t >> 6, l = t & 63;
    const int wi = w >> 1, wj = w & 1;

    // staging: wave w owns rows [w*32, w*32+32); swizzle chunk c ^= (row>>1)&3 (2-way = free)
    const int rs0 = (w << 5) + (l >> 2);
    const int kq = ((l & 3) ^ ((l >> 3) & 3)) << 3;
    const ushort* gA0 = Z + (size_t)(i0 + rs0) * 256 + kq;
    const ushort* gA1 = gA0 + 16 * 256;
    const ushort* gB0 = Z + (size_t)(j0 + rs0) * 256 + kq;
    const ushort* gB1 = gB0 + 16 * 256;
    const int ldo0 = (w << 5) << 5;
    const int ldo1 = ldo0 + (16 << 5);

    const int lane_m = l & 15, lane_q = l >> 4;
    int aoff[4], boff[4];
#pragma unroll
    for (int f = 0; f < 4; ++f) {
        const int ra = (wi << 6) + (f << 4) + lane_m;
        aoff[f] = (ra << 5) + ((lane_q ^ ((ra >> 1) & 3)) << 3);
        const int rb = (wj << 6) + (f << 4) + lane_m;
        boff[f] = (rb << 5) + ((lane_q ^ ((rb >> 1) & 3)) << 3);
    }

    floatx4 accf[4][4];
#pragma unroll
    for (int fi = 0; fi < 4; ++fi)
#pragma unroll
        for (int fj = 0; fj < 4; ++fj) accf[fi][fj] = (floatx4){0.f, 0.f, 0.f, 0.f};

    for (int ck = 0; ck < 8; ++ck) {
        if (ck > 0) __syncthreads();           // prior chunk's reads done before overwrite
        const int ko = ck << 5;
        glds16(gA0 + ko, &lA[ldo0]); glds16(gA1 + ko, &lA[ldo1]);
        glds16(gB0 + ko, &lB[ldo0]); glds16(gB1 + ko, &lB[ldo1]);
        __syncthreads();                       // drains vmcnt: staging visible
        short8 af[4], bfr[4];
#pragma unroll
        for (int f = 0; f < 4; ++f) {
            af[f]  = *(const short8*)(&lA[aoff[f]]);
            bfr[f] = *(const short8*)(&lB[boff[f]]);
        }
#pragma unroll
        for (int fi = 0; fi < 4; ++fi)
#pragma unroll
            for (int fj = 0; fj < 4; ++fj)
                accf[fi][fj] = __builtin_amdgcn_mfma_f32_16x16x32_bf16(af[fi], bfr[fj], accf[fi][fj], 0, 0, 0);
    }

    // ---- epilogue ----
    float c2[NSIG];
#pragma unroll
    for (int k = 0; k < NSIG; ++k) c2[k] = (-0.5f / sigmas[k]) * 1.44269504f;

    const float* nA = norms + i0 + (wi << 6);
    const float* nB = norms + j0 + (wj << 6);
    const bool diag = (bi == bj);
    const float sgn2 = ((bi < 32) == (bj < 32)) ? 2.f : -2.f;

#pragma unroll
    for (int fi = 0; fi < 4; ++fi) {
        const floatx4 ni4 = *(const floatx4*)(nA + (fi << 4) + (lane_q << 2));
#pragma unroll
        for (int fj = 0; fj < 4; ++fj) {
            const float njs = nB[(fj << 4) + lane_m];
#pragma unroll
            for (int v = 0; v < 4; ++v) {
                float d = fmaf(-2.f, accf[fi][fj][v], ni4[v] + njs);
                d = fmaxf(d, 0.f);
                if (diag) {
                    const int dif = ((wi - wj) << 6) + ((fi - fj) << 4) + ((lane_q << 2) + v) - lane_m;
                    d = (dif < 0) ? d : 3.0e9f;   // keep strictly-upper pairs only
                }
                accf[fi][fj][v] = d;
            }
        }
    }

    float dmin = accf[0][0][0];
#pragma unroll
    for (int fi = 0; fi < 4; ++fi)
#pragma unroll
        for (int fj = 0; fj < 4; ++fj)
#pragma unroll
            for (int v = 0; v < 4; ++v) dmin = fminf(dmin, accf[fi][fj][v]);
#pragma unroll
    for (int off = 1; off < 64; off <<= 1) dmin = fminf(dmin, __shfl_xor(dmin, off, 64));

    float lsum = 0.f;
#pragma unroll
    for (int k = 0; k < NSIG; ++k) {
        if (c2[k] * dmin >= -126.f) {      // wave-uniform: skip if every exp underflows (exact in fp32)
#pragma unroll
            for (int fi = 0; fi < 4; ++fi)
#pragma unroll
                for (int fj = 0; fj < 4; ++fj)
#pragma unroll
                    for (int v = 0; v < 4; ++v)
                        lsum += __builtin_amdgcn_exp2f(c2[k] * accf[fi][fj][v]);
        }
    }
    lsum *= sgn2;

#pragma unroll
    for (int off = 32; off > 0; off >>= 1) lsum += __shfl_down(lsum, off, 64);
    if (l == 0) wsum[w] = lsum;
    __syncthreads();
    if (t == 0) atomicAdd(acc, (double)(wsum[0] + wsum[1] + wsum[2] + wsum[3]));
}

__global__ void finalize_kernel(const double* __restrict__ acc, float* __restrict__ out) {
    out[0] = (float)((*acc + 8192.0 * NSIG) * (1.0 / (4096.0 * 4096.0)));
}

extern "C" void kernel_launch(void* const* d_in, const int* in_sizes, int n_in,
                              void* d_out, int out_size, void* d_ws, size_t ws_size,
                              hipStream_t stream) {
    const float* x   = (const float*)d_in[0];
    const float* y   = (const float*)d_in[1];
    const float* sig = (const float*)d_in[2];

    ushort* Z    = (ushort*)d_ws;                                   // 4 MiB
    float* norms = (float*)((char*)d_ws + (size_t)8192 * 256 * 2);  // 32 KiB
    double* acc  = (double*)((char*)norms + 8192 * sizeof(float));
    float* out   = (float*)d_out;

    prep_kernel<<<512, 256, 0, stream>>>(x, y, Z, norms, acc);
    gemm_epi<<<NBLK, 256, 0, stream>>>(Z, norms, sig, acc);
    finalize_kernel<<<1, 1, 0, stream>>>(acc, out);
}